// Round 3
// baseline (262.114 us; speedup 1.0000x reference)
//
#include <hip/hip_runtime.h>

// Problem constants
#define N_TOTAL   65536   // B*H*W = 64*32*32
#define HW_SZ     1024    // H*W
#define CDIM      64      // embedding dim (= C)
#define K_CODES   1024
#define OUT_ELEMS 4194304 // 64*64*32*32
#define NBLK_OUT  (OUT_ELEMS / 256)   // 16384
#define QT        64      // queries per argmin block
#define CHUNK     128     // codes staged per LDS chunk
#define TAU       0.05f   // rescue margin (>> 1.6e-2 worst-case bf16x3 error)

// ws layout (bytes):
//   0      : enorm[1024]  float
//   4096   : hist[1024]   uint
//   8192   : counter      uint
//   12288  : e_hi[1024*64] bf16-as-short
//   143360 : e_lo[1024*64] bf16-as-short
//   274432 : idx[65536]   int
//   536576 : list[65536]  ushort (flagged queries)
//   664576 : partials[16384] float

typedef __attribute__((ext_vector_type(8))) short short8;
typedef __attribute__((ext_vector_type(4))) float f32x4;

__device__ __forceinline__ unsigned short f2bf(float x) {
    unsigned u = __float_as_uint(x);
    unsigned r = (u + 0x7FFFu + ((u >> 16) & 1u)) >> 16;   // RNE
    return (unsigned short)r;
}
__device__ __forceinline__ float bf2f(unsigned short h) {
    return __uint_as_float(((unsigned)h) << 16);
}

// ---------------------------------------------------------------- k_prep ----
// norms + bf16 hi/lo split of embeddings + zero hist/counter
__global__ void k_prep(const float* __restrict__ emb, float* __restrict__ enorm,
                       short* __restrict__ ehi, short* __restrict__ elo,
                       unsigned int* __restrict__ hist, unsigned int* __restrict__ counter) {
    int k = blockIdx.x * blockDim.x + threadIdx.x;   // 0..1023
    const float4* row = (const float4*)(emb + k * CDIM);
    float s = 0.f;
#pragma unroll
    for (int i = 0; i < 16; ++i) {
        float4 v = row[i];
        s += v.x * v.x + v.y * v.y + v.z * v.z + v.w * v.w;
        short h[4], l[4];
        float vv[4] = {v.x, v.y, v.z, v.w};
#pragma unroll
        for (int j = 0; j < 4; ++j) {
            unsigned short hh = f2bf(vv[j]);
            h[j] = (short)hh;
            l[j] = (short)f2bf(vv[j] - bf2f(hh));
        }
        *(short4*)&ehi[k * CDIM + i * 4] = make_short4(h[0], h[1], h[2], h[3]);
        *(short4*)&elo[k * CDIM + i * 4] = make_short4(l[0], l[1], l[2], l[3]);
    }
    enorm[k] = s;
    hist[k] = 0u;
    if (k == 0) *counter = 0u;
}

// -------------------------------------------------------------- k_argmin ----
// 256 threads = 4 waves. Block: 64 queries x all 1024 codes (bf16x3 MFMA).
// x (A operand) fully register-resident; e chunks of 128 codes in swizzled LDS.
// LDS rows: 64 shorts = 8 x 16B blocks; block bb stored at slot bb^(row&7).
__global__ __launch_bounds__(256, 2)
void k_argmin(const float* __restrict__ x,
              const short* __restrict__ ehi, const short* __restrict__ elo,
              const float* __restrict__ enorm, int* __restrict__ out_idx,
              unsigned short* __restrict__ list, unsigned int* __restrict__ counter) {
    __shared__ __align__(16) short es[2][CHUNK * CDIM];  // 2 x 16 KB
    __shared__ __align__(16) short xs[2][QT * CDIM];     // 2 x 8 KB

    const int tid  = threadIdx.x;
    const int lane = tid & 63;
    const int w    = tid >> 6;        // wave 0..3
    const int quad = lane >> 4;
    const int col  = lane & 15;

    const int n0  = blockIdx.x * QT;
    const int b   = n0 >> 10;
    const int hw0 = n0 & 1023;

    // ---- stage x tile: transpose (c,hw)->(q,c), split hi/lo, swizzled ----
#pragma unroll
    for (int p = 0; p < 4; ++p) {
        int c  = p * 16 + (tid >> 4);
        int q0 = (tid & 15) * 4;
        float4 v = *(const float4*)(x + b * (CDIM * HW_SZ) + c * HW_SZ + hw0 + q0);
        float vv[4] = {v.x, v.y, v.z, v.w};
#pragma unroll
        for (int j = 0; j < 4; ++j) {
            int q = q0 + j;
            unsigned short h = f2bf(vv[j]);
            unsigned short l = f2bf(vv[j] - bf2f(h));
            int off = q * CDIM + (((c >> 3) ^ (q & 7)) << 3) + (c & 7);
            xs[0][off] = (short)h;
            xs[1][off] = (short)l;
        }
    }
    __syncthreads();

    // ---- A fragments (register-resident for whole kernel) ----
    // A[m = lane&15][k = quad*8+j]; m = rt*16 + col
    short8 afr[4][2][2];   // [rowtile][kchunk][hi/lo]
#pragma unroll
    for (int rt = 0; rt < 4; ++rt) {
        int m = rt * 16 + col;
#pragma unroll
        for (int kc = 0; kc < 2; ++kc) {
            int bb  = kc * 4 + quad;
            int off = m * CDIM + ((bb ^ (m & 7)) << 3);
            afr[rt][kc][0] = *(const short8*)&xs[0][off];
            afr[rt][kc][1] = *(const short8*)&xs[1][off];
        }
    }

    // ---- top-2 tracking per owned query row ----
    float d1[16], d2[16];
    int   i1[16];
#pragma unroll
    for (int t = 0; t < 16; ++t) { d1[t] = 3.4e38f; d2[t] = 3.4e38f; i1[t] = 0; }

    for (int chunk = 0; chunk < K_CODES / CHUNK; ++chunk) {
        const int cb = chunk * CHUNK;
        __syncthreads();   // previous chunk's reads complete
        // stage 128 codes hi+lo (16KB each), swizzled 16B blocks
#pragma unroll
        for (int i = 0; i < 4; ++i) {
            int linS = (i * 256 + tid) * 8;        // short index, 16B granules
            int row  = linS >> 6;
            int bb   = (linS & 63) >> 3;
            int dst  = row * CDIM + ((bb ^ (row & 7)) << 3);
            *(short8*)&es[0][dst] = *(const short8*)&ehi[cb * CDIM + linS];
            *(short8*)&es[1][dst] = *(const short8*)&elo[cb * CDIM + linS];
        }
        __syncthreads();

        // wave w owns codes [cb + w*32, +32) : 2 tiles of 16
#pragma unroll
        for (int ct = 0; ct < 2; ++ct) {
            const int r0 = w * 32 + ct * 16;
            const int r  = r0 + col;              // B row (code within chunk)
            short8 bfr[2][2];
#pragma unroll
            for (int kc = 0; kc < 2; ++kc) {
                int bb  = kc * 4 + quad;
                int off = r * CDIM + ((bb ^ (r & 7)) << 3);
                bfr[kc][0] = *(const short8*)&es[0][off];
                bfr[kc][1] = *(const short8*)&es[1][off];
            }
            const int mycode = cb + r;
            const float en   = enorm[mycode];
#pragma unroll
            for (int rt = 0; rt < 4; ++rt) {
                f32x4 acc = {0.f, 0.f, 0.f, 0.f};
                acc = __builtin_amdgcn_mfma_f32_16x16x32_bf16(afr[rt][0][1], bfr[0][0], acc, 0, 0, 0);
                acc = __builtin_amdgcn_mfma_f32_16x16x32_bf16(afr[rt][0][0], bfr[0][1], acc, 0, 0, 0);
                acc = __builtin_amdgcn_mfma_f32_16x16x32_bf16(afr[rt][0][0], bfr[0][0], acc, 0, 0, 0);
                acc = __builtin_amdgcn_mfma_f32_16x16x32_bf16(afr[rt][1][1], bfr[1][0], acc, 0, 0, 0);
                acc = __builtin_amdgcn_mfma_f32_16x16x32_bf16(afr[rt][1][0], bfr[1][1], acc, 0, 0, 0);
                acc = __builtin_amdgcn_mfma_f32_16x16x32_bf16(afr[rt][1][0], bfr[1][0], acc, 0, 0, 0);
                // C/D: col = lane&15 (code), row = quad*4 + reg (query within 16)
#pragma unroll
                for (int reg = 0; reg < 4; ++reg) {
                    float d = en - 2.f * acc[reg];
                    int t = rt * 4 + reg;
                    if (d < d1[t])      { d2[t] = d1[t]; d1[t] = d; i1[t] = mycode; }
                    else if (d < d2[t]) { d2[t] = d; }
                }
            }
        }
    }

    // ---- reduce across the 16 cols (lanes quad*16..quad*16+15) ----
#pragma unroll
    for (int t = 0; t < 16; ++t) {
        float a1 = d1[t], a2 = d2[t];
        int ai = i1[t];
#pragma unroll
        for (int off = 1; off < 16; off <<= 1) {
            float o1 = __shfl_xor(a1, off, 64);
            float o2 = __shfl_xor(a2, off, 64);
            int   oi = __shfl_xor(ai, off, 64);
            if (o1 < a1 || (o1 == a1 && oi < ai)) {
                float loser = a1; a2 = fminf(fminf(a2, o2), loser); a1 = o1; ai = oi;
            } else {
                a2 = fminf(fminf(a2, o2), o1);
            }
        }
        d1[t] = a1; d2[t] = a2; i1[t] = ai;
    }

    // ---- per-wave results -> LDS (reuse xs region) ----
    float* rd1 = (float*)xs;           // [256]
    float* rd2 = rd1 + 256;            // [256]
    int*   ri  = (int*)(rd2 + 256);    // [256]
    __syncthreads();
    if (col == 0) {
#pragma unroll
        for (int rt = 0; rt < 4; ++rt)
#pragma unroll
            for (int reg = 0; reg < 4; ++reg) {
                int t = rt * 4 + reg;
                int m = rt * 16 + quad * 4 + reg;
                rd1[w * QT + m] = d1[t];
                rd2[w * QT + m] = d2[t];
                ri [w * QT + m] = i1[t];
            }
    }
    __syncthreads();

    // ---- final 4-way merge + margin flag (wave 0 only) ----
    if (tid < QT) {
        float a1 = rd1[tid], a2 = rd2[tid];
        int ai = ri[tid];
#pragma unroll
        for (int ww = 1; ww < 4; ++ww) {
            float o1 = rd1[ww * QT + tid], o2 = rd2[ww * QT + tid];
            int oi = ri[ww * QT + tid];
            if (o1 < a1 || (o1 == a1 && oi < ai)) {
                float loser = a1; a2 = fminf(fminf(a2, o2), loser); a1 = o1; ai = oi;
            } else {
                a2 = fminf(fminf(a2, o2), o1);
            }
        }
        out_idx[n0 + tid] = ai;
        bool flag = (a2 - a1) < TAU;
        unsigned long long mask = __ballot(flag);
        int cnt = __popcll(mask);
        unsigned base = 0;
        if (tid == 0 && cnt) base = atomicAdd(counter, (unsigned)cnt);
        base = (unsigned)__shfl((int)base, 0, 64);
        if (flag) {
            int pre = __popcll(mask & ((1ull << tid) - 1ull));
            list[base + pre] = (unsigned short)(n0 + tid);
        }
    }
}

// -------------------------------------------------------------- k_rescue ----
// One wave per flagged query: exact fp32 distances over all 1024 codes.
__global__ void k_rescue(const float* __restrict__ x, const float* __restrict__ emb,
                         const float* __restrict__ enorm,
                         const unsigned short* __restrict__ list,
                         const unsigned int* __restrict__ counter,
                         int* __restrict__ out_idx) {
    const int lane = threadIdx.x & 63;
    const int gw   = (blockIdx.x * blockDim.x + threadIdx.x) >> 6;  // global wave id
    const int nw   = (gridDim.x * blockDim.x) >> 6;
    const unsigned cnt = *counter;
    for (unsigned wi = gw; wi < cnt; wi += nw) {
        const int q  = list[wi];
        const int b  = q >> 10;
        const int hw = q & 1023;
        const float* xq = x + b * (CDIM * HW_SZ) + hw;
        float4 xr[16];
#pragma unroll
        for (int c4 = 0; c4 < 16; ++c4)
            xr[c4] = make_float4(xq[(c4 * 4 + 0) * HW_SZ], xq[(c4 * 4 + 1) * HW_SZ],
                                 xq[(c4 * 4 + 2) * HW_SZ], xq[(c4 * 4 + 3) * HW_SZ]);
        float dmin = 3.4e38f;
        int   imin = 0;
        for (int i = 0; i < 16; ++i) {
            int k = lane + 64 * i;                 // ascending per lane
            const float4* er = (const float4*)(emb + k * CDIM);
            float dot = 0.f;
#pragma unroll
            for (int c4 = 0; c4 < 16; ++c4) {
                float4 e = er[c4];
                dot += xr[c4].x * e.x + xr[c4].y * e.y + xr[c4].z * e.z + xr[c4].w * e.w;
            }
            float d = enorm[k] - 2.f * dot;
            if (d < dmin) { dmin = d; imin = k; }
        }
#pragma unroll
        for (int off = 1; off < 64; off <<= 1) {
            float od = __shfl_xor(dmin, off, 64);
            int   oi = __shfl_xor(imin, off, 64);
            if (od < dmin || (od == dmin && oi < imin)) { dmin = od; imin = oi; }
        }
        if (lane == 0) out_idx[q] = imin;
    }
}

// -------------------------------------------------------------- k_output ----
__global__ void k_output(const float* __restrict__ x, const float* __restrict__ emb,
                         const int* __restrict__ idx, float* __restrict__ out,
                         float* __restrict__ partials) {
    int gid = blockIdx.x * 256 + threadIdx.x;
    int hw  = gid & 1023;
    int c   = (gid >> 10) & 63;
    int b   = gid >> 16;
    int n   = b * HW_SZ + hw;
    int k   = idx[n];
    float q  = emb[k * CDIM + c];
    float xv = x[gid];
    out[gid] = q;
    float dv = q - xv;
    float d2 = dv * dv;

    __shared__ float red[4];
#pragma unroll
    for (int off = 32; off; off >>= 1) d2 += __shfl_down(d2, off, 64);
    if ((threadIdx.x & 63) == 0) red[threadIdx.x >> 6] = d2;
    __syncthreads();
    if (threadIdx.x == 0) partials[blockIdx.x] = red[0] + red[1] + red[2] + red[3];
}

// ---------------------------------------------------------------- k_hist ----
__global__ void k_hist(const int* __restrict__ idx, unsigned int* __restrict__ hist) {
    __shared__ unsigned int lh[K_CODES];
    int tid = threadIdx.x;
#pragma unroll
    for (int i = 0; i < 4; ++i) lh[i * 256 + tid] = 0u;
    __syncthreads();
    for (int i = blockIdx.x * 256 + tid; i < N_TOTAL; i += 64 * 256)
        atomicAdd(&lh[idx[i]], 1u);
    __syncthreads();
#pragma unroll
    for (int i = 0; i < 4; ++i) {
        unsigned int v = lh[i * 256 + tid];
        if (v) atomicAdd(&hist[i * 256 + tid], v);
    }
}

// --------------------------------------------------------------- k_final ----
__global__ void k_final(const unsigned int* __restrict__ hist,
                        const float* __restrict__ partials, float* __restrict__ out2) {
    int tid = threadIdx.x;   // 256
    float ss = 0.f;
#pragma unroll
    for (int i = 0; i < 64; ++i) ss += partials[i * 256 + tid];
    float s = 0.f;
#pragma unroll
    for (int i = 0; i < 4; ++i) {
        float p = (float)hist[i * 256 + tid] * (1.0f / 65536.0f);
        s += p * logf(p + 1e-10f);
    }
    __shared__ float redA[4], redB[4];
#pragma unroll
    for (int off = 32; off; off >>= 1) {
        s  += __shfl_down(s, off, 64);
        ss += __shfl_down(ss, off, 64);
    }
    if ((tid & 63) == 0) { redA[tid >> 6] = s; redB[tid >> 6] = ss; }
    __syncthreads();
    if (tid == 0) {
        float tot = redA[0] + redA[1] + redA[2] + redA[3];
        float sse = redB[0] + redB[1] + redB[2] + redB[3];
        out2[0] = 1.25f * sse * (1.0f / (float)OUT_ELEMS);
        out2[1] = expf(-tot);
    }
}

// ---------------------------------------------------------------- launch ----
extern "C" void kernel_launch(void* const* d_in, const int* in_sizes, int n_in,
                              void* d_out, int out_size, void* d_ws, size_t ws_size,
                              hipStream_t stream) {
    const float* x   = (const float*)d_in[0];
    const float* emb = (const float*)d_in[1];
    float* out = (float*)d_out;
    char* ws = (char*)d_ws;
    float*          enorm    = (float*)(ws);
    unsigned int*   hist     = (unsigned int*)(ws + 4096);
    unsigned int*   counter  = (unsigned int*)(ws + 8192);
    short*          ehi      = (short*)(ws + 12288);
    short*          elo      = (short*)(ws + 143360);
    int*            idx      = (int*)(ws + 274432);
    unsigned short* list     = (unsigned short*)(ws + 536576);
    float*          partials = (float*)(ws + 664576);

    k_prep  <<<K_CODES / 256, 256, 0, stream>>>(emb, enorm, ehi, elo, hist, counter);
    k_argmin<<<N_TOTAL / QT, 256, 0, stream>>>(x, ehi, elo, enorm, idx, list, counter);
    k_rescue<<<128, 256, 0, stream>>>(x, emb, enorm, list, counter, idx);
    k_output<<<NBLK_OUT, 256, 0, stream>>>(x, emb, idx, out, partials);
    k_hist  <<<64, 256, 0, stream>>>(idx, hist);
    k_final <<<1, 256, 0, stream>>>(hist, partials, out + OUT_ELEMS);
}

// Round 4
// 227.869 us; speedup vs baseline: 1.1503x; 1.1503x over previous
//
#include <hip/hip_runtime.h>

// Problem constants
#define N_TOTAL   65536   // B*H*W = 64*32*32
#define HW_SZ     1024    // H*W
#define CDIM      64      // embedding dim (= C)
#define K_CODES   1024
#define OUT_ELEMS 4194304 // 64*64*32*32
#define QT        64      // queries per argmin block
#define CHUNK     128     // codes staged per LDS chunk
#define TAU       0.02f   // rescue margin (>=10x the ~2e-3 worst-case bf16x3 error)
#define RESCUE_BLOCKS 2048

// ws layout (bytes):
//   0      : enorm[1024]  float
//   4096   : hist[1024]   uint
//   8192   : counter      uint
//   12288  : e_hi[1024*64] bf16-as-short
//   143360 : e_lo[1024*64] bf16-as-short
//   274432 : idx[65536]   int
//   536576 : list[65536]  ushort (flagged queries)
//   664576 : partials[4096] float

typedef __attribute__((ext_vector_type(8))) short short8;
typedef __attribute__((ext_vector_type(4))) float f32x4;

__device__ __forceinline__ unsigned short f2bf(float x) {
    unsigned u = __float_as_uint(x);
    unsigned r = (u + 0x7FFFu + ((u >> 16) & 1u)) >> 16;   // RNE
    return (unsigned short)r;
}
__device__ __forceinline__ float bf2f(unsigned short h) {
    return __uint_as_float(((unsigned)h) << 16);
}

// ---------------------------------------------------------------- k_prep ----
// 64 blocks x 256: thread = 4 consecutive emb elements; 16 lanes per code.
__global__ void k_prep(const float* __restrict__ emb, float* __restrict__ enorm,
                       short* __restrict__ ehi, short* __restrict__ elo,
                       unsigned int* __restrict__ hist, unsigned int* __restrict__ counter) {
    int gid = blockIdx.x * 256 + threadIdx.x;        // 0..16383
    float4 v = *(const float4*)(emb + gid * 4);
    float s = v.x * v.x + v.y * v.y + v.z * v.z + v.w * v.w;
#pragma unroll
    for (int off = 1; off < 16; off <<= 1) s += __shfl_xor(s, off, 64);
    if ((gid & 15) == 0) enorm[gid >> 4] = s;        // k = gid/16

    float vv[4] = {v.x, v.y, v.z, v.w};
    short h[4], l[4];
#pragma unroll
    for (int j = 0; j < 4; ++j) {
        unsigned short hh = f2bf(vv[j]);
        h[j] = (short)hh;
        l[j] = (short)f2bf(vv[j] - bf2f(hh));
    }
    *(short4*)&ehi[gid * 4] = make_short4(h[0], h[1], h[2], h[3]);
    *(short4*)&elo[gid * 4] = make_short4(l[0], l[1], l[2], l[3]);

    if (gid < K_CODES) hist[gid] = 0u;
    if (gid == 0) *counter = 0u;
}

// -------------------------------------------------------------- k_argmin ----
// (unchanged this round — clean counter attribution)
__global__ __launch_bounds__(256, 2)
void k_argmin(const float* __restrict__ x,
              const short* __restrict__ ehi, const short* __restrict__ elo,
              const float* __restrict__ enorm, int* __restrict__ out_idx,
              unsigned short* __restrict__ list, unsigned int* __restrict__ counter) {
    __shared__ __align__(16) short es[2][CHUNK * CDIM];  // 2 x 16 KB
    __shared__ __align__(16) short xs[2][QT * CDIM];     // 2 x 8 KB

    const int tid  = threadIdx.x;
    const int lane = tid & 63;
    const int w    = tid >> 6;
    const int quad = lane >> 4;
    const int col  = lane & 15;

    const int n0  = blockIdx.x * QT;
    const int b   = n0 >> 10;
    const int hw0 = n0 & 1023;

#pragma unroll
    for (int p = 0; p < 4; ++p) {
        int c  = p * 16 + (tid >> 4);
        int q0 = (tid & 15) * 4;
        float4 v = *(const float4*)(x + b * (CDIM * HW_SZ) + c * HW_SZ + hw0 + q0);
        float vv[4] = {v.x, v.y, v.z, v.w};
#pragma unroll
        for (int j = 0; j < 4; ++j) {
            int q = q0 + j;
            unsigned short h = f2bf(vv[j]);
            unsigned short l = f2bf(vv[j] - bf2f(h));
            int off = q * CDIM + (((c >> 3) ^ (q & 7)) << 3) + (c & 7);
            xs[0][off] = (short)h;
            xs[1][off] = (short)l;
        }
    }
    __syncthreads();

    short8 afr[4][2][2];
#pragma unroll
    for (int rt = 0; rt < 4; ++rt) {
        int m = rt * 16 + col;
#pragma unroll
        for (int kc = 0; kc < 2; ++kc) {
            int bb  = kc * 4 + quad;
            int off = m * CDIM + ((bb ^ (m & 7)) << 3);
            afr[rt][kc][0] = *(const short8*)&xs[0][off];
            afr[rt][kc][1] = *(const short8*)&xs[1][off];
        }
    }

    float d1[16], d2[16];
    int   i1[16];
#pragma unroll
    for (int t = 0; t < 16; ++t) { d1[t] = 3.4e38f; d2[t] = 3.4e38f; i1[t] = 0; }

    for (int chunk = 0; chunk < K_CODES / CHUNK; ++chunk) {
        const int cb = chunk * CHUNK;
        __syncthreads();
#pragma unroll
        for (int i = 0; i < 4; ++i) {
            int linS = (i * 256 + tid) * 8;
            int row  = linS >> 6;
            int bb   = (linS & 63) >> 3;
            int dst  = row * CDIM + ((bb ^ (row & 7)) << 3);
            *(short8*)&es[0][dst] = *(const short8*)&ehi[cb * CDIM + linS];
            *(short8*)&es[1][dst] = *(const short8*)&elo[cb * CDIM + linS];
        }
        __syncthreads();

#pragma unroll
        for (int ct = 0; ct < 2; ++ct) {
            const int r0 = w * 32 + ct * 16;
            const int r  = r0 + col;
            short8 bfr[2][2];
#pragma unroll
            for (int kc = 0; kc < 2; ++kc) {
                int bb  = kc * 4 + quad;
                int off = r * CDIM + ((bb ^ (r & 7)) << 3);
                bfr[kc][0] = *(const short8*)&es[0][off];
                bfr[kc][1] = *(const short8*)&es[1][off];
            }
            const int mycode = cb + r;
            const float en   = enorm[mycode];
#pragma unroll
            for (int rt = 0; rt < 4; ++rt) {
                f32x4 acc = {0.f, 0.f, 0.f, 0.f};
                acc = __builtin_amdgcn_mfma_f32_16x16x32_bf16(afr[rt][0][1], bfr[0][0], acc, 0, 0, 0);
                acc = __builtin_amdgcn_mfma_f32_16x16x32_bf16(afr[rt][0][0], bfr[0][1], acc, 0, 0, 0);
                acc = __builtin_amdgcn_mfma_f32_16x16x32_bf16(afr[rt][0][0], bfr[0][0], acc, 0, 0, 0);
                acc = __builtin_amdgcn_mfma_f32_16x16x32_bf16(afr[rt][1][1], bfr[1][0], acc, 0, 0, 0);
                acc = __builtin_amdgcn_mfma_f32_16x16x32_bf16(afr[rt][1][0], bfr[1][1], acc, 0, 0, 0);
                acc = __builtin_amdgcn_mfma_f32_16x16x32_bf16(afr[rt][1][0], bfr[1][0], acc, 0, 0, 0);
#pragma unroll
                for (int reg = 0; reg < 4; ++reg) {
                    float d = en - 2.f * acc[reg];
                    int t = rt * 4 + reg;
                    if (d < d1[t])      { d2[t] = d1[t]; d1[t] = d; i1[t] = mycode; }
                    else if (d < d2[t]) { d2[t] = d; }
                }
            }
        }
    }

#pragma unroll
    for (int t = 0; t < 16; ++t) {
        float a1 = d1[t], a2 = d2[t];
        int ai = i1[t];
#pragma unroll
        for (int off = 1; off < 16; off <<= 1) {
            float o1 = __shfl_xor(a1, off, 64);
            float o2 = __shfl_xor(a2, off, 64);
            int   oi = __shfl_xor(ai, off, 64);
            if (o1 < a1 || (o1 == a1 && oi < ai)) {
                float loser = a1; a2 = fminf(fminf(a2, o2), loser); a1 = o1; ai = oi;
            } else {
                a2 = fminf(fminf(a2, o2), o1);
            }
        }
        d1[t] = a1; d2[t] = a2; i1[t] = ai;
    }

    float* rd1 = (float*)xs;
    float* rd2 = rd1 + 256;
    int*   ri  = (int*)(rd2 + 256);
    __syncthreads();
    if (col == 0) {
#pragma unroll
        for (int rt = 0; rt < 4; ++rt)
#pragma unroll
            for (int reg = 0; reg < 4; ++reg) {
                int t = rt * 4 + reg;
                int m = rt * 16 + quad * 4 + reg;
                rd1[w * QT + m] = d1[t];
                rd2[w * QT + m] = d2[t];
                ri [w * QT + m] = i1[t];
            }
    }
    __syncthreads();

    if (tid < QT) {
        float a1 = rd1[tid], a2 = rd2[tid];
        int ai = ri[tid];
#pragma unroll
        for (int ww = 1; ww < 4; ++ww) {
            float o1 = rd1[ww * QT + tid], o2 = rd2[ww * QT + tid];
            int oi = ri[ww * QT + tid];
            if (o1 < a1 || (o1 == a1 && oi < ai)) {
                float loser = a1; a2 = fminf(fminf(a2, o2), loser); a1 = o1; ai = oi;
            } else {
                a2 = fminf(fminf(a2, o2), o1);
            }
        }
        out_idx[n0 + tid] = ai;
        bool flag = (a2 - a1) < TAU;
        unsigned long long mask = __ballot(flag);
        int cnt = __popcll(mask);
        unsigned base = 0;
        if (tid == 0 && cnt) base = atomicAdd(counter, (unsigned)cnt);
        base = (unsigned)__shfl((int)base, 0, 64);
        if (flag) {
            int pre = __popcll(mask & ((1ull << tid) - 1ull));
            list[base + pre] = (unsigned short)(n0 + tid);
        }
    }
}

// -------------------------------------------------------------- k_rescue ----
// Block-per-query: 256 threads, thread t handles codes {t, t+256, t+512, t+768}
// exactly in fp32; x staged in LDS; lexicographic (d, idx) block argmin.
__global__ void k_rescue(const float* __restrict__ x, const float* __restrict__ emb,
                         const float* __restrict__ enorm,
                         const unsigned short* __restrict__ list,
                         const unsigned int* __restrict__ counter,
                         int* __restrict__ out_idx) {
    __shared__ __align__(16) float xls[CDIM];
    __shared__ float rdd[4];
    __shared__ int   rdi[4];
    const int tid  = threadIdx.x;
    const int lane = tid & 63;
    const int w    = tid >> 6;
    const unsigned cnt = *counter;

    for (unsigned qi = blockIdx.x; qi < cnt; qi += RESCUE_BLOCKS) {
        const int q  = list[qi];
        const int b  = q >> 10;
        const int hw = q & 1023;
        if (tid < CDIM) xls[tid] = x[b * (CDIM * HW_SZ) + tid * HW_SZ + hw];
        __syncthreads();

        float dmin = 3.4e38f;
        int   imin = 0;
#pragma unroll
        for (int it = 0; it < 4; ++it) {
            const int k = tid + 256 * it;               // ascending per thread
            const float4* er = (const float4*)(emb + k * CDIM);
            const float4* xr = (const float4*)xls;
            float dot = 0.f;
#pragma unroll
            for (int c4 = 0; c4 < 16; ++c4) {
                float4 e = er[c4];
                float4 xv = xr[c4];
                dot += xv.x * e.x + xv.y * e.y + xv.z * e.z + xv.w * e.w;
            }
            float d = enorm[k] - 2.f * dot;
            if (d < dmin) { dmin = d; imin = k; }
        }
#pragma unroll
        for (int off = 1; off < 64; off <<= 1) {
            float od = __shfl_xor(dmin, off, 64);
            int   oi = __shfl_xor(imin, off, 64);
            if (od < dmin || (od == dmin && oi < imin)) { dmin = od; imin = oi; }
        }
        if (lane == 0) { rdd[w] = dmin; rdi[w] = imin; }
        __syncthreads();
        if (tid == 0) {
            float bd = rdd[0]; int bi = rdi[0];
#pragma unroll
            for (int ww = 1; ww < 4; ++ww) {
                if (rdd[ww] < bd || (rdd[ww] == bd && rdi[ww] < bi)) { bd = rdd[ww]; bi = rdi[ww]; }
            }
            out_idx[q] = bi;
        }
        __syncthreads();   // protect xls/rdd for next iteration
    }
}

// -------------------------------------------------------------- k_output ----
// 4096 blocks x 256: thread = float4 (4 consecutive hw). Coalesced 16B/lane.
__global__ void k_output(const float* __restrict__ x, const float* __restrict__ emb,
                         const int* __restrict__ idx, float* __restrict__ out,
                         float* __restrict__ partials) {
    int gid  = blockIdx.x * 256 + threadIdx.x;
    int base = gid * 4;
    int hw   = base & 1023;
    int c    = (base >> 10) & 63;
    int b    = base >> 16;
    int n0   = b * HW_SZ + hw;
    int4   k4 = *(const int4*)&idx[n0];
    float4 xv = *(const float4*)&x[base];
    float4 qv;
    qv.x = emb[k4.x * CDIM + c];
    qv.y = emb[k4.y * CDIM + c];
    qv.z = emb[k4.z * CDIM + c];
    qv.w = emb[k4.w * CDIM + c];
    *(float4*)&out[base] = qv;
    float dx = qv.x - xv.x, dy = qv.y - xv.y, dz = qv.z - xv.z, dw = qv.w - xv.w;
    float d2 = dx * dx + dy * dy + dz * dz + dw * dw;

    __shared__ float red[4];
#pragma unroll
    for (int off = 32; off; off >>= 1) d2 += __shfl_down(d2, off, 64);
    if ((threadIdx.x & 63) == 0) red[threadIdx.x >> 6] = d2;
    __syncthreads();
    if (threadIdx.x == 0) partials[blockIdx.x] = red[0] + red[1] + red[2] + red[3];
}

// ---------------------------------------------------------------- k_hist ----
__global__ void k_hist(const int* __restrict__ idx, unsigned int* __restrict__ hist) {
    __shared__ unsigned int lh[K_CODES];
    int tid = threadIdx.x;
#pragma unroll
    for (int i = 0; i < 4; ++i) lh[i * 256 + tid] = 0u;
    __syncthreads();
    for (int i = blockIdx.x * 256 + tid; i < N_TOTAL; i += 64 * 256)
        atomicAdd(&lh[idx[i]], 1u);
    __syncthreads();
#pragma unroll
    for (int i = 0; i < 4; ++i) {
        unsigned int v = lh[i * 256 + tid];
        if (v) atomicAdd(&hist[i * 256 + tid], v);
    }
}

// --------------------------------------------------------------- k_final ----
__global__ void k_final(const unsigned int* __restrict__ hist,
                        const float* __restrict__ partials, float* __restrict__ out2) {
    int tid = threadIdx.x;   // 256
    float ss = 0.f;
#pragma unroll
    for (int i = 0; i < 16; ++i) ss += partials[i * 256 + tid];
    float s = 0.f;
#pragma unroll
    for (int i = 0; i < 4; ++i) {
        float p = (float)hist[i * 256 + tid] * (1.0f / 65536.0f);
        s += p * logf(p + 1e-10f);
    }
    __shared__ float redA[4], redB[4];
#pragma unroll
    for (int off = 32; off; off >>= 1) {
        s  += __shfl_down(s, off, 64);
        ss += __shfl_down(ss, off, 64);
    }
    if ((tid & 63) == 0) { redA[tid >> 6] = s; redB[tid >> 6] = ss; }
    __syncthreads();
    if (tid == 0) {
        float tot = redA[0] + redA[1] + redA[2] + redA[3];
        float sse = redB[0] + redB[1] + redB[2] + redB[3];
        out2[0] = 1.25f * sse * (1.0f / (float)OUT_ELEMS);
        out2[1] = expf(-tot);
    }
}

// ---------------------------------------------------------------- launch ----
extern "C" void kernel_launch(void* const* d_in, const int* in_sizes, int n_in,
                              void* d_out, int out_size, void* d_ws, size_t ws_size,
                              hipStream_t stream) {
    const float* x   = (const float*)d_in[0];
    const float* emb = (const float*)d_in[1];
    float* out = (float*)d_out;
    char* ws = (char*)d_ws;
    float*          enorm    = (float*)(ws);
    unsigned int*   hist     = (unsigned int*)(ws + 4096);
    unsigned int*   counter  = (unsigned int*)(ws + 8192);
    short*          ehi      = (short*)(ws + 12288);
    short*          elo      = (short*)(ws + 143360);
    int*            idx      = (int*)(ws + 274432);
    unsigned short* list     = (unsigned short*)(ws + 536576);
    float*          partials = (float*)(ws + 664576);

    k_prep  <<<64, 256, 0, stream>>>(emb, enorm, ehi, elo, hist, counter);
    k_argmin<<<N_TOTAL / QT, 256, 0, stream>>>(x, ehi, elo, enorm, idx, list, counter);
    k_rescue<<<RESCUE_BLOCKS, 256, 0, stream>>>(x, emb, enorm, list, counter, idx);
    k_output<<<OUT_ELEMS / 1024, 256, 0, stream>>>(x, emb, idx, out, partials);
    k_hist  <<<64, 256, 0, stream>>>(idx, hist);
    k_final <<<1, 256, 0, stream>>>(hist, partials, out + OUT_ELEMS);
}

// Round 5
// 216.957 us; speedup vs baseline: 1.2081x; 1.0503x over previous
//
#include <hip/hip_runtime.h>

// Problem constants
#define N_TOTAL   65536   // B*H*W = 64*32*32
#define HW_SZ     1024    // H*W
#define CDIM      64      // embedding dim (= C)
#define K_CODES   1024
#define OUT_ELEMS 4194304 // 64*64*32*32
#define QT        64      // queries per argmin block
#define CHUNK     128     // codes staged per LDS chunk
#define TAU       0.02f   // rescue margin (>=10x the ~2e-3 worst-case bf16x3 error)
#define RESCUE_BLOCKS 2048

// ws layout (bytes):
//   0      : enorm[1024]  float
//   4096   : hist[1024]   uint
//   8192   : counter      uint
//   12288  : e_hi[1024*64] bf16-as-short
//   143360 : e_lo[1024*64] bf16-as-short
//   274432 : idx[65536]   int
//   536576 : list[65536]  ushort (flagged queries)
//   664576 : partials[1024] float

typedef __attribute__((ext_vector_type(8))) short short8;
typedef __attribute__((ext_vector_type(4))) float f32x4;

__device__ __forceinline__ unsigned short f2bf(float x) {
    unsigned u = __float_as_uint(x);
    unsigned r = (u + 0x7FFFu + ((u >> 16) & 1u)) >> 16;   // RNE
    return (unsigned short)r;
}
__device__ __forceinline__ float bf2f(unsigned short h) {
    return __uint_as_float(((unsigned)h) << 16);
}

// ---------------------------------------------------------------- k_prep ----
__global__ void k_prep(const float* __restrict__ emb, float* __restrict__ enorm,
                       short* __restrict__ ehi, short* __restrict__ elo,
                       unsigned int* __restrict__ hist, unsigned int* __restrict__ counter) {
    int gid = blockIdx.x * 256 + threadIdx.x;        // 0..16383
    float4 v = *(const float4*)(emb + gid * 4);
    float s = v.x * v.x + v.y * v.y + v.z * v.z + v.w * v.w;
#pragma unroll
    for (int off = 1; off < 16; off <<= 1) s += __shfl_xor(s, off, 64);
    if ((gid & 15) == 0) enorm[gid >> 4] = s;        // k = gid/16

    float vv[4] = {v.x, v.y, v.z, v.w};
    short h[4], l[4];
#pragma unroll
    for (int j = 0; j < 4; ++j) {
        unsigned short hh = f2bf(vv[j]);
        h[j] = (short)hh;
        l[j] = (short)f2bf(vv[j] - bf2f(hh));
    }
    *(short4*)&ehi[gid * 4] = make_short4(h[0], h[1], h[2], h[3]);
    *(short4*)&elo[gid * 4] = make_short4(l[0], l[1], l[2], l[3]);

    if (gid < K_CODES) hist[gid] = 0u;
    if (gid == 0) *counter = 0u;
}

// -------------------------------------------------------------- k_argmin ----
// 256 thr = 4 waves; 64 queries x 1024 codes, bf16x3 MFMA, branchless top-2.
__global__ __launch_bounds__(256, 3)
void k_argmin(const float* __restrict__ x,
              const short* __restrict__ ehi, const short* __restrict__ elo,
              const float* __restrict__ enorm, int* __restrict__ out_idx,
              unsigned short* __restrict__ list, unsigned int* __restrict__ counter) {
    __shared__ __align__(16) short es[2][CHUNK * CDIM];  // 2 x 16 KB
    __shared__ __align__(16) short xs[2][QT * CDIM];     // 2 x 8 KB

    const int tid  = threadIdx.x;
    const int lane = tid & 63;
    const int w    = tid >> 6;
    const int quad = lane >> 4;
    const int col  = lane & 15;

    const int n0  = blockIdx.x * QT;
    const int b   = n0 >> 10;
    const int hw0 = n0 & 1023;

#pragma unroll
    for (int p = 0; p < 4; ++p) {
        int c  = p * 16 + (tid >> 4);
        int q0 = (tid & 15) * 4;
        float4 v = *(const float4*)(x + b * (CDIM * HW_SZ) + c * HW_SZ + hw0 + q0);
        float vv[4] = {v.x, v.y, v.z, v.w};
#pragma unroll
        for (int j = 0; j < 4; ++j) {
            int q = q0 + j;
            unsigned short h = f2bf(vv[j]);
            unsigned short l = f2bf(vv[j] - bf2f(h));
            int off = q * CDIM + (((c >> 3) ^ (q & 7)) << 3) + (c & 7);
            xs[0][off] = (short)h;
            xs[1][off] = (short)l;
        }
    }
    __syncthreads();

    short8 afr[4][2][2];
#pragma unroll
    for (int rt = 0; rt < 4; ++rt) {
        int m = rt * 16 + col;
#pragma unroll
        for (int kc = 0; kc < 2; ++kc) {
            int bb  = kc * 4 + quad;
            int off = m * CDIM + ((bb ^ (m & 7)) << 3);
            afr[rt][kc][0] = *(const short8*)&xs[0][off];
            afr[rt][kc][1] = *(const short8*)&xs[1][off];
        }
    }

    float d1[16], d2[16];
    int   i1[16];
#pragma unroll
    for (int t = 0; t < 16; ++t) { d1[t] = 3.4e38f; d2[t] = 3.4e38f; i1[t] = 0; }

    for (int chunk = 0; chunk < K_CODES / CHUNK; ++chunk) {
        const int cb = chunk * CHUNK;
        __syncthreads();
#pragma unroll
        for (int i = 0; i < 4; ++i) {
            int linS = (i * 256 + tid) * 8;
            int row  = linS >> 6;
            int bb   = (linS & 63) >> 3;
            int dst  = row * CDIM + ((bb ^ (row & 7)) << 3);
            *(short8*)&es[0][dst] = *(const short8*)&ehi[cb * CDIM + linS];
            *(short8*)&es[1][dst] = *(const short8*)&elo[cb * CDIM + linS];
        }
        __syncthreads();

#pragma unroll
        for (int ct = 0; ct < 2; ++ct) {
            const int r0 = w * 32 + ct * 16;
            const int r  = r0 + col;
            short8 bfr[2][2];
#pragma unroll
            for (int kc = 0; kc < 2; ++kc) {
                int bb  = kc * 4 + quad;
                int off = r * CDIM + ((bb ^ (r & 7)) << 3);
                bfr[kc][0] = *(const short8*)&es[0][off];
                bfr[kc][1] = *(const short8*)&es[1][off];
            }
            const int mycode = cb + r;
            const float en   = enorm[mycode];
#pragma unroll
            for (int rt = 0; rt < 4; ++rt) {
                f32x4 acc = {0.f, 0.f, 0.f, 0.f};
                acc = __builtin_amdgcn_mfma_f32_16x16x32_bf16(afr[rt][0][1], bfr[0][0], acc, 0, 0, 0);
                acc = __builtin_amdgcn_mfma_f32_16x16x32_bf16(afr[rt][0][0], bfr[0][1], acc, 0, 0, 0);
                acc = __builtin_amdgcn_mfma_f32_16x16x32_bf16(afr[rt][0][0], bfr[0][0], acc, 0, 0, 0);
                acc = __builtin_amdgcn_mfma_f32_16x16x32_bf16(afr[rt][1][1], bfr[1][0], acc, 0, 0, 0);
                acc = __builtin_amdgcn_mfma_f32_16x16x32_bf16(afr[rt][1][0], bfr[1][1], acc, 0, 0, 0);
                acc = __builtin_amdgcn_mfma_f32_16x16x32_bf16(afr[rt][1][0], bfr[1][0], acc, 0, 0, 0);
                // branchless top-2 update (min/med3 idiom, no divergence)
#pragma unroll
                for (int reg = 0; reg < 4; ++reg) {
                    int t = rt * 4 + reg;
                    float d   = __builtin_fmaf(acc[reg], -2.f, en);
                    float d1o = d1[t];
                    float lo  = fminf(d, d1o);
                    float hi  = fmaxf(d, d1o);
                    i1[t] = (d < d1o) ? mycode : i1[t];
                    d1[t] = lo;
                    d2[t] = fmaxf(lo, fminf(hi, d2[t]));   // med3(d, d1o, d2o)
                }
            }
        }
    }

#pragma unroll
    for (int t = 0; t < 16; ++t) {
        float a1 = d1[t], a2 = d2[t];
        int ai = i1[t];
#pragma unroll
        for (int off = 1; off < 16; off <<= 1) {
            float o1 = __shfl_xor(a1, off, 64);
            float o2 = __shfl_xor(a2, off, 64);
            int   oi = __shfl_xor(ai, off, 64);
            if (o1 < a1 || (o1 == a1 && oi < ai)) {
                float loser = a1; a2 = fminf(fminf(a2, o2), loser); a1 = o1; ai = oi;
            } else {
                a2 = fminf(fminf(a2, o2), o1);
            }
        }
        d1[t] = a1; d2[t] = a2; i1[t] = ai;
    }

    float* rd1 = (float*)xs;
    float* rd2 = rd1 + 256;
    int*   ri  = (int*)(rd2 + 256);
    __syncthreads();
    if (col == 0) {
#pragma unroll
        for (int rt = 0; rt < 4; ++rt)
#pragma unroll
            for (int reg = 0; reg < 4; ++reg) {
                int t = rt * 4 + reg;
                int m = rt * 16 + quad * 4 + reg;
                rd1[w * QT + m] = d1[t];
                rd2[w * QT + m] = d2[t];
                ri [w * QT + m] = i1[t];
            }
    }
    __syncthreads();

    if (tid < QT) {
        float a1 = rd1[tid], a2 = rd2[tid];
        int ai = ri[tid];
#pragma unroll
        for (int ww = 1; ww < 4; ++ww) {
            float o1 = rd1[ww * QT + tid], o2 = rd2[ww * QT + tid];
            int oi = ri[ww * QT + tid];
            if (o1 < a1 || (o1 == a1 && oi < ai)) {
                float loser = a1; a2 = fminf(fminf(a2, o2), loser); a1 = o1; ai = oi;
            } else {
                a2 = fminf(fminf(a2, o2), o1);
            }
        }
        out_idx[n0 + tid] = ai;
        bool flag = (a2 - a1) < TAU;
        unsigned long long mask = __ballot(flag);
        int cnt = __popcll(mask);
        unsigned base = 0;
        if (tid == 0 && cnt) base = atomicAdd(counter, (unsigned)cnt);
        base = (unsigned)__shfl((int)base, 0, 64);
        if (flag) {
            int pre = __popcll(mask & ((1ull << tid) - 1ull));
            list[base + pre] = (unsigned short)(n0 + tid);
        }
    }
}

// -------------------------------------------------------------- k_rescue ----
__global__ void k_rescue(const float* __restrict__ x, const float* __restrict__ emb,
                         const float* __restrict__ enorm,
                         const unsigned short* __restrict__ list,
                         const unsigned int* __restrict__ counter,
                         int* __restrict__ out_idx) {
    __shared__ __align__(16) float xls[CDIM];
    __shared__ float rdd[4];
    __shared__ int   rdi[4];
    const int tid  = threadIdx.x;
    const int lane = tid & 63;
    const int w    = tid >> 6;
    const unsigned cnt = *counter;

    for (unsigned qi = blockIdx.x; qi < cnt; qi += RESCUE_BLOCKS) {
        const int q  = list[qi];
        const int b  = q >> 10;
        const int hw = q & 1023;
        if (tid < CDIM) xls[tid] = x[b * (CDIM * HW_SZ) + tid * HW_SZ + hw];
        __syncthreads();

        float dmin = 3.4e38f;
        int   imin = 0;
#pragma unroll
        for (int it = 0; it < 4; ++it) {
            const int k = tid + 256 * it;
            const float4* er = (const float4*)(emb + k * CDIM);
            const float4* xr = (const float4*)xls;
            float dot = 0.f;
#pragma unroll
            for (int c4 = 0; c4 < 16; ++c4) {
                float4 e = er[c4];
                float4 xv = xr[c4];
                dot += xv.x * e.x + xv.y * e.y + xv.z * e.z + xv.w * e.w;
            }
            float d = enorm[k] - 2.f * dot;
            if (d < dmin) { dmin = d; imin = k; }
        }
#pragma unroll
        for (int off = 1; off < 64; off <<= 1) {
            float od = __shfl_xor(dmin, off, 64);
            int   oi = __shfl_xor(imin, off, 64);
            if (od < dmin || (od == dmin && oi < imin)) { dmin = od; imin = oi; }
        }
        if (lane == 0) { rdd[w] = dmin; rdi[w] = imin; }
        __syncthreads();
        if (tid == 0) {
            float bd = rdd[0]; int bi = rdi[0];
#pragma unroll
            for (int ww = 1; ww < 4; ++ww) {
                if (rdd[ww] < bd || (rdd[ww] == bd && rdi[ww] < bi)) { bd = rdd[ww]; bi = rdi[ww]; }
            }
            out_idx[q] = bi;
        }
        __syncthreads();
    }
}

// -------------------------------------------------------------- k_output ----
// Block = 64 queries (one b, 64-aligned hw range). Gather whole emb rows
// (float4), LDS transpose (pitch 72 floats, 16B-aligned), coalesced writes.
__global__ void k_output(const float* __restrict__ x, const float* __restrict__ emb,
                         const int* __restrict__ idx, float* __restrict__ out,
                         float* __restrict__ partials) {
    __shared__ float tile[64 * 72];   // 18 KB
    __shared__ int   ids[64];
    const int tid = threadIdx.x;
    const int n0  = blockIdx.x * 64;
    const int b   = n0 >> 10;
    const int hw0 = n0 & 1023;

    if (tid < 64) ids[tid] = idx[n0 + tid];
    __syncthreads();

    {   // gather: thread = (q = tid>>2, j = tid&3), 4 float4 each
        int q = tid >> 2, j = tid & 3;
        const float4* er = (const float4*)(emb + ids[q] * CDIM);
#pragma unroll
        for (int p = 0; p < 4; ++p) {
            float4 v = er[j * 4 + p];
            *(float4*)&tile[q * 72 + (j * 4 + p) * 4] = v;
        }
    }
    __syncthreads();

    // write + SSE: thread owns channel c = tid>>2; 4 float4 along hw
    float sse = 0.f;
    const int c = tid >> 2;
    const float* xb = x + b * (CDIM * HW_SZ) + c * HW_SZ + hw0;
    float*       ob = out + b * (CDIM * HW_SZ) + c * HW_SZ + hw0;
#pragma unroll
    for (int p = 0; p < 4; ++p) {
        int q = ((tid & 3) + p * 4) * 4;   // 0..60
        float4 v;
        v.x = tile[(q + 0) * 72 + c];
        v.y = tile[(q + 1) * 72 + c];
        v.z = tile[(q + 2) * 72 + c];
        v.w = tile[(q + 3) * 72 + c];
        float4 xv = *(const float4*)&xb[q];
        *(float4*)&ob[q] = v;
        float dx = v.x - xv.x, dy = v.y - xv.y, dz = v.z - xv.z, dw = v.w - xv.w;
        sse += dx * dx + dy * dy + dz * dz + dw * dw;
    }

    __shared__ float red[4];
#pragma unroll
    for (int off = 32; off; off >>= 1) sse += __shfl_down(sse, off, 64);
    if ((tid & 63) == 0) red[tid >> 6] = sse;
    __syncthreads();
    if (tid == 0) partials[blockIdx.x] = red[0] + red[1] + red[2] + red[3];
}

// ---------------------------------------------------------------- k_hist ----
__global__ void k_hist(const int* __restrict__ idx, unsigned int* __restrict__ hist) {
    __shared__ unsigned int lh[K_CODES];
    int tid = threadIdx.x;
#pragma unroll
    for (int i = 0; i < 4; ++i) lh[i * 256 + tid] = 0u;
    __syncthreads();
    for (int i = blockIdx.x * 256 + tid; i < N_TOTAL; i += 64 * 256)
        atomicAdd(&lh[idx[i]], 1u);
    __syncthreads();
#pragma unroll
    for (int i = 0; i < 4; ++i) {
        unsigned int v = lh[i * 256 + tid];
        if (v) atomicAdd(&hist[i * 256 + tid], v);
    }
}

// --------------------------------------------------------------- k_final ----
__global__ void k_final(const unsigned int* __restrict__ hist,
                        const float* __restrict__ partials, float* __restrict__ out2) {
    int tid = threadIdx.x;   // 256
    float ss = 0.f;
#pragma unroll
    for (int i = 0; i < 4; ++i) ss += partials[i * 256 + tid];
    float s = 0.f;
#pragma unroll
    for (int i = 0; i < 4; ++i) {
        float p = (float)hist[i * 256 + tid] * (1.0f / 65536.0f);
        s += p * logf(p + 1e-10f);
    }
    __shared__ float redA[4], redB[4];
#pragma unroll
    for (int off = 32; off; off >>= 1) {
        s  += __shfl_down(s, off, 64);
        ss += __shfl_down(ss, off, 64);
    }
    if ((tid & 63) == 0) { redA[tid >> 6] = s; redB[tid >> 6] = ss; }
    __syncthreads();
    if (tid == 0) {
        float tot = redA[0] + redA[1] + redA[2] + redA[3];
        float sse = redB[0] + redB[1] + redB[2] + redB[3];
        out2[0] = 1.25f * sse * (1.0f / (float)OUT_ELEMS);
        out2[1] = expf(-tot);
    }
}

// ---------------------------------------------------------------- launch ----
extern "C" void kernel_launch(void* const* d_in, const int* in_sizes, int n_in,
                              void* d_out, int out_size, void* d_ws, size_t ws_size,
                              hipStream_t stream) {
    const float* x   = (const float*)d_in[0];
    const float* emb = (const float*)d_in[1];
    float* out = (float*)d_out;
    char* ws = (char*)d_ws;
    float*          enorm    = (float*)(ws);
    unsigned int*   hist     = (unsigned int*)(ws + 4096);
    unsigned int*   counter  = (unsigned int*)(ws + 8192);
    short*          ehi      = (short*)(ws + 12288);
    short*          elo      = (short*)(ws + 143360);
    int*            idx      = (int*)(ws + 274432);
    unsigned short* list     = (unsigned short*)(ws + 536576);
    float*          partials = (float*)(ws + 664576);

    k_prep  <<<64, 256, 0, stream>>>(emb, enorm, ehi, elo, hist, counter);
    k_argmin<<<N_TOTAL / QT, 256, 0, stream>>>(x, ehi, elo, enorm, idx, list, counter);
    k_rescue<<<RESCUE_BLOCKS, 256, 0, stream>>>(x, emb, enorm, list, counter, idx);
    k_output<<<N_TOTAL / 64, 256, 0, stream>>>(x, emb, idx, out, partials);
    k_hist  <<<64, 256, 0, stream>>>(idx, hist);
    k_final <<<1, 256, 0, stream>>>(hist, partials, out + OUT_ELEMS);
}